// Round 1
// baseline (392.151 us; speedup 1.0000x reference)
//
#include <hip/hip_runtime.h>
#include <hip/hip_bf16.h>
#include <math.h>

#define NH 8
#define SDIM 9
#define NSEG 16
#define NATOM 512
#define NEDGE 8192
#define CIN 128
#define CHN 256
#define DH 32
#define FDIM 288            // SDIM*DH
#define EPS 1e-7f
#define SCALE 0.10206207261596577f   // sqrt(32/3)/32

// ---------------- block reduce helpers (blockDim.x == 256) ----------------
__device__ inline float blockReduceMax(float v, float* red) {
    #pragma unroll
    for (int off = 32; off; off >>= 1) v = fmaxf(v, __shfl_xor(v, off, 64));
    int lane = threadIdx.x & 63, wid = threadIdx.x >> 6;
    if (lane == 0) red[wid] = v;
    __syncthreads();
    v = fmaxf(fmaxf(red[0], red[1]), fmaxf(red[2], red[3]));
    __syncthreads();
    return v;
}
__device__ inline float blockReduceSum(float v, float* red) {
    #pragma unroll
    for (int off = 32; off; off >>= 1) v += __shfl_xor(v, off, 64);
    int lane = threadIdx.x & 63, wid = threadIdx.x >> 6;
    if (lane == 0) red[wid] = v;
    __syncthreads();
    v = red[0] + red[1] + red[2] + red[3];
    __syncthreads();
    return v;
}

// ---------------- K0: per-edge table precompute ----------------
__global__ void edge_pre(const int* __restrict__ emap, const int* __restrict__ batch,
                         const float* __restrict__ envelope, const float* __restrict__ attn_bias,
                         float* __restrict__ biasE, float* __restrict__ envE,
                         float* __restrict__ env2E, int* __restrict__ segStart) {
    int e = blockIdx.x * 256 + threadIdx.x;
    if (e >= NEDGE) return;
    int em = emap[e];
    float ev = envelope[em];
    envE[e] = ev;
    env2E[e] = ev * ev;
    #pragma unroll
    for (int h = 0; h < NH; ++h) biasE[h * NEDGE + e] = attn_bias[h * NEDGE + em];
    int b = batch[e];
    if (e == 0) {
        for (int s2 = 0; s2 <= b; ++s2) segStart[s2] = 0;
    } else {
        int bp = batch[e - 1];
        for (int s2 = bp + 1; s2 <= b; ++s2) segStart[s2] = e;
    }
    if (e == NEDGE - 1) {
        for (int s2 = b + 1; s2 <= NSEG; ++s2) segStart[s2] = NEDGE;
    }
}

// ---------------- K1: so3_linear (CIN=128 -> CHN=256), write (H,N,F) layout ----------------
__global__ void __launch_bounds__(256) so3lin_in(const float* __restrict__ x, const float* __restrict__ W,
                                                const float* __restrict__ b, float* __restrict__ out) {
    const int n0 = blockIdx.x * 8;
    const int s = blockIdx.y;
    const int l = (s == 0) ? 0 : ((s < 4) ? 1 : 2);
    __shared__ float xs[8][CIN];
    const int tid = threadIdx.x;
    for (int idx = tid; idx < 8 * CIN; idx += 256) {
        int r = idx >> 7, i = idx & 127;
        xs[r][i] = x[((size_t)(n0 + r) * SDIM + s) * CIN + i];
    }
    __syncthreads();
    const int o = tid;
    const float* Wl = W + (size_t)l * CIN * CHN + o;
    float acc[8] = {0, 0, 0, 0, 0, 0, 0, 0};
    #pragma unroll 4
    for (int i = 0; i < CIN; ++i) {
        float w = Wl[(size_t)i * CHN];
        #pragma unroll
        for (int r = 0; r < 8; ++r) acc[r] += xs[r][i] * w;
    }
    float bb = (s == 0) ? b[o] : 0.f;
    const int h = o >> 5, dj = o & 31;
    #pragma unroll
    for (int r = 0; r < 8; ++r)
        out[((size_t)h * NATOM + (n0 + r)) * FDIM + s * DH + dj] = acc[r] + bb;
}

// ---------------- K2: scoresA[h][n][m] = SCALE * dot(qh[h,n,:], kh[h,m,:]) ----------------
__global__ void __launch_bounds__(256) gemm_scores(const float* __restrict__ qh, const float* __restrict__ kh,
                                                   float* __restrict__ scoresA) {
    const int h = blockIdx.z;
    const int m0 = blockIdx.x * 64;
    const int n0 = blockIdx.y * 64;
    const float* A = qh + (size_t)h * NATOM * FDIM;
    const float* B = kh + (size_t)h * NATOM * FDIM;
    __shared__ float As[64][17];
    __shared__ float Bs[64][17];
    const int tid = threadIdx.x;
    const int tx = tid & 15, ty = tid >> 4;
    const int lr = tid >> 2;
    const int lc = (tid & 3) << 2;
    float acc[4][4] = {};
    for (int kk = 0; kk < FDIM; kk += 16) {
        float4 a4 = *(const float4*)(A + (size_t)(n0 + lr) * FDIM + kk + lc);
        float4 b4 = *(const float4*)(B + (size_t)(m0 + lr) * FDIM + kk + lc);
        As[lr][lc + 0] = a4.x; As[lr][lc + 1] = a4.y; As[lr][lc + 2] = a4.z; As[lr][lc + 3] = a4.w;
        Bs[lr][lc + 0] = b4.x; Bs[lr][lc + 1] = b4.y; Bs[lr][lc + 2] = b4.z; Bs[lr][lc + 3] = b4.w;
        __syncthreads();
        #pragma unroll
        for (int k2 = 0; k2 < 16; ++k2) {
            float a[4], b[4];
            #pragma unroll
            for (int i = 0; i < 4; ++i) a[i] = As[ty * 4 + i][k2];
            #pragma unroll
            for (int j = 0; j < 4; ++j) b[j] = Bs[tx * 4 + j][k2];
            #pragma unroll
            for (int i = 0; i < 4; ++i)
                #pragma unroll
                for (int j = 0; j < 4; ++j) acc[i][j] += a[i] * b[j];
        }
        __syncthreads();
    }
    #pragma unroll
    for (int i = 0; i < 4; ++i) {
        size_t rowo = ((size_t)h * NATOM + n0 + ty * 4 + i) * NATOM + m0 + tx * 4;
        #pragma unroll
        for (int j = 0; j < 4; ++j) scoresA[rowo + j] = acc[i][j] * SCALE;
    }
}

// ---------------- K3: segmented softmax + edge->atom aggregation (in-place on scoresA) ----------------
__global__ void __launch_bounds__(256) softmax_agg(float* __restrict__ scoresA, const int* __restrict__ am,
                                                   const float* __restrict__ biasE, const float* __restrict__ envE,
                                                   const float* __restrict__ env2E, const int* __restrict__ segStart) {
    const int n0 = blockIdx.x * 4;
    const int h = blockIdx.y;
    __shared__ float srow[4][NATOM];
    __shared__ float arow[4][NATOM];
    __shared__ float red[4];
    __shared__ int segS[NSEG + 1];
    const int tid = threadIdx.x;
    float* base = scoresA + ((size_t)h * NATOM + n0) * NATOM;
    for (int i = tid; i < 4 * NATOM; i += 256) {
        int r = i >> 9, c = i & 511;
        srow[r][c] = base[(size_t)r * NATOM + c];
        arow[r][c] = 0.f;
    }
    if (tid <= NSEG) segS[tid] = segStart[tid];
    __syncthreads();
    const float* bE = biasE + (size_t)h * NEDGE;
    for (int seg = 0; seg < NSEG; ++seg) {
        int st = segS[seg], en = segS[seg + 1];
        if (en <= st) continue;
        float lm[4] = {-1e30f, -1e30f, -1e30f, -1e30f};
        for (int e = st + tid; e < en; e += 256) {
            int m = am[e];
            float bb = bE[e];
            #pragma unroll
            for (int r = 0; r < 4; ++r) lm[r] = fmaxf(lm[r], srow[r][m] + bb);
        }
        float mx[4];
        #pragma unroll
        for (int r = 0; r < 4; ++r) mx[r] = blockReduceMax(lm[r], red);
        float ls[4] = {0, 0, 0, 0};
        for (int e = st + tid; e < en; e += 256) {
            int m = am[e];
            float bb = bE[e];
            float ev = envE[e];
            #pragma unroll
            for (int r = 0; r < 4; ++r) ls[r] += ev * __expf(srow[r][m] + bb - mx[r]);
        }
        float inv[4];
        #pragma unroll
        for (int r = 0; r < 4; ++r) {
            float den = blockReduceSum(ls[r], red);
            inv[r] = 1.0f / (den + 1e-16f);
        }
        for (int e = st + tid; e < en; e += 256) {
            int m = am[e];
            float bb = bE[e];
            float e2 = env2E[e];
            #pragma unroll
            for (int r = 0; r < 4; ++r) {
                float w = e2 * __expf(srow[r][m] + bb - mx[r]) * inv[r];
                atomicAdd(&arow[r][m], w);
            }
        }
        __syncthreads();
    }
    for (int i = tid; i < 4 * NATOM; i += 256) {
        int r = i >> 9, c = i & 511;
        base[(size_t)r * NATOM + c] = arow[r][c];
    }
}

// ---------------- K4: attnOut[n][s][h*32+dj] = sum_m attnA[h,n,m]*vh[h,m,f], f=s*32+dj ----------------
__global__ void __launch_bounds__(256) gemm_out(const float* __restrict__ attnA, const float* __restrict__ vh,
                                                float* __restrict__ attnOut) {
    const int h = blockIdx.z;
    const int f0 = blockIdx.x * 64;
    const int n0 = blockIdx.y * 64;
    const float* A = attnA + (size_t)h * NATOM * NATOM;
    const float* B = vh + (size_t)h * NATOM * FDIM;
    __shared__ float As[64][17];
    __shared__ float Bs[16][68];
    const int tid = threadIdx.x;
    const int tx = tid & 15, ty = tid >> 4;
    const int ar = tid >> 2, ac = (tid & 3) << 2;
    const int bk_ = tid >> 4, bc = (tid & 15) << 2;
    const bool bok = (f0 + bc) < FDIM;
    float acc[4][4] = {};
    for (int kk = 0; kk < NATOM; kk += 16) {
        float4 a4 = *(const float4*)(A + (size_t)(n0 + ar) * NATOM + kk + ac);
        As[ar][ac + 0] = a4.x; As[ar][ac + 1] = a4.y; As[ar][ac + 2] = a4.z; As[ar][ac + 3] = a4.w;
        if (bok) {
            float4 b4 = *(const float4*)(B + (size_t)(kk + bk_) * FDIM + f0 + bc);
            Bs[bk_][bc + 0] = b4.x; Bs[bk_][bc + 1] = b4.y; Bs[bk_][bc + 2] = b4.z; Bs[bk_][bc + 3] = b4.w;
        } else {
            Bs[bk_][bc + 0] = 0.f; Bs[bk_][bc + 1] = 0.f; Bs[bk_][bc + 2] = 0.f; Bs[bk_][bc + 3] = 0.f;
        }
        __syncthreads();
        #pragma unroll
        for (int k2 = 0; k2 < 16; ++k2) {
            float4 b4 = *(const float4*)(&Bs[k2][tx * 4]);
            float a[4];
            #pragma unroll
            for (int i = 0; i < 4; ++i) a[i] = As[ty * 4 + i][k2];
            #pragma unroll
            for (int i = 0; i < 4; ++i) {
                acc[i][0] += a[i] * b4.x;
                acc[i][1] += a[i] * b4.y;
                acc[i][2] += a[i] * b4.z;
                acc[i][3] += a[i] * b4.w;
            }
        }
        __syncthreads();
    }
    #pragma unroll
    for (int i = 0; i < 4; ++i) {
        int n = n0 + ty * 4 + i;
        #pragma unroll
        for (int j = 0; j < 4; ++j) {
            int f = f0 + tx * 4 + j;
            if (f < FDIM) {
                int s = f >> 5, dj = f & 31;
                attnOut[((size_t)n * SDIM + s) * CHN + h * DH + dj] = acc[i][j];
            }
        }
    }
}

// ---------------- K5: equivariant layernorm ----------------
__global__ void __launch_bounds__(256) eqln(const float* __restrict__ xin, const float* __restrict__ gamma,
                                            const float* __restrict__ beta, float* __restrict__ outn) {
    const int n = blockIdx.x;
    const int c = threadIdx.x;
    __shared__ float red[4];
    float xv[SDIM];
    #pragma unroll
    for (int s = 0; s < SDIM; ++s) xv[s] = xin[((size_t)n * SDIM + s) * CHN + c];
    // l = 0
    float mu = blockReduceSum(xv[0], red) * (1.0f / CHN);
    float dv = xv[0] - mu;
    float var = blockReduceSum(dv * dv, red) * (1.0f / CHN);
    float y0 = dv / sqrtf(var + EPS) * gamma[c] + beta[c];
    outn[(size_t)n * SDIM * CHN + c] = y0;
    // l = 1 (rows 1..3)
    float n2 = (xv[1] * xv[1] + xv[2] * xv[2] + xv[3] * xv[3]) * (1.0f / 3.0f);
    float ms = blockReduceSum(n2, red) * (1.0f / CHN);
    float inv1 = 1.0f / sqrtf(ms + EPS);
    #pragma unroll
    for (int s = 1; s < 4; ++s)
        outn[((size_t)n * SDIM + s) * CHN + c] = xv[s] * inv1 * gamma[CHN + c];
    // l = 2 (rows 4..8)
    float n22 = (xv[4] * xv[4] + xv[5] * xv[5] + xv[6] * xv[6] + xv[7] * xv[7] + xv[8] * xv[8]) * (1.0f / 5.0f);
    float ms2 = blockReduceSum(n22, red) * (1.0f / CHN);
    float inv2 = 1.0f / sqrtf(ms2 + EPS);
    #pragma unroll
    for (int s = 4; s < SDIM; ++s)
        outn[((size_t)n * SDIM + s) * CHN + c] = xv[s] * inv2 * gamma[2 * CHN + c];
}

// ---------------- K6: final so3_linear (CHN=256 -> CIN=128) ----------------
__global__ void __launch_bounds__(128) so3lin_out(const float* __restrict__ xn, const float* __restrict__ Wo,
                                                  const float* __restrict__ bo, float* __restrict__ out) {
    const int n0 = blockIdx.x * 8;
    const int s = blockIdx.y;
    const int l = (s == 0) ? 0 : ((s < 4) ? 1 : 2);
    __shared__ float xs[8][CHN];
    const int tid = threadIdx.x;
    for (int idx = tid; idx < 8 * CHN; idx += 128) {
        int r = idx >> 8, i = idx & 255;
        xs[r][i] = xn[((size_t)(n0 + r) * SDIM + s) * CHN + i];
    }
    __syncthreads();
    const int o = tid;
    const float* Wl = Wo + (size_t)l * CHN * CIN + o;
    float acc[8] = {0, 0, 0, 0, 0, 0, 0, 0};
    #pragma unroll 4
    for (int i = 0; i < CHN; ++i) {
        float w = Wl[(size_t)i * CIN];
        #pragma unroll
        for (int r = 0; r < 8; ++r) acc[r] += xs[r][i] * w;
    }
    float bb = (s == 0) ? bo[o] : 0.f;
    #pragma unroll
    for (int r = 0; r < 8; ++r)
        out[((size_t)(n0 + r) * SDIM + s) * CIN + o] = acc[r] + bb;
}

extern "C" void kernel_launch(void* const* d_in, const int* in_sizes, int n_in,
                              void* d_out, int out_size, void* d_ws, size_t ws_size,
                              hipStream_t stream) {
    const float* q = (const float*)d_in[0];
    const float* k = (const float*)d_in[1];
    const float* v = (const float*)d_in[2];
    const float* envelope = (const float*)d_in[3];
    const float* attn_bias = (const float*)d_in[4];
    const int* atom_index = (const int*)d_in[5];
    const int* batch_index = (const int*)d_in[6];
    const int* edge_map = (const int*)d_in[7];
    const float* Wq = (const float*)d_in[8];
    const float* bq = (const float*)d_in[9];
    const float* Wk = (const float*)d_in[10];
    const float* bk = (const float*)d_in[11];
    const float* Wv = (const float*)d_in[12];
    const float* bv = (const float*)d_in[13];
    const float* gamma = (const float*)d_in[14];
    const float* beta = (const float*)d_in[15];
    const float* Wo = (const float*)d_in[16];
    const float* bo = (const float*)d_in[17];
    float* out = (float*)d_out;

    const size_t SZ_HNF = (size_t)NH * NATOM * FDIM;      // 1179648
    const size_t SZ_HNN = (size_t)NH * NATOM * NATOM;     // 2097152
    float* ws = (float*)d_ws;
    float* qh = ws;
    float* kh = qh + SZ_HNF;
    float* vh = kh + SZ_HNF;
    float* scoresA = vh + SZ_HNF;            // also attnA (in-place)
    float* biasE = scoresA + SZ_HNN;         // NH*NEDGE
    float* envE = biasE + (size_t)NH * NEDGE;
    float* env2E = envE + NEDGE;
    int* segStart = (int*)(env2E + NEDGE);
    float* attnOut = kh;                      // reuse after K2
    float* normed = qh;                       // reuse after K2

    size_t needed = (3 * SZ_HNF + SZ_HNN + (size_t)NH * NEDGE + 2 * NEDGE + 64) * 4;
    if (ws_size < needed) return;

    edge_pre<<<NEDGE / 256, 256, 0, stream>>>(edge_map, batch_index, envelope, attn_bias,
                                              biasE, envE, env2E, segStart);
    dim3 gLin(NATOM / 8, SDIM);
    so3lin_in<<<gLin, 256, 0, stream>>>(q, Wq, bq, qh);
    so3lin_in<<<gLin, 256, 0, stream>>>(k, Wk, bk, kh);
    so3lin_in<<<gLin, 256, 0, stream>>>(v, Wv, bv, vh);
    gemm_scores<<<dim3(NATOM / 64, NATOM / 64, NH), 256, 0, stream>>>(qh, kh, scoresA);
    softmax_agg<<<dim3(NATOM / 4, NH), 256, 0, stream>>>(scoresA, atom_index, biasE, envE, env2E, segStart);
    gemm_out<<<dim3((FDIM + 63) / 64, NATOM / 64, NH), 256, 0, stream>>>(scoresA, vh, attnOut);
    eqln<<<NATOM, 256, 0, stream>>>(attnOut, gamma, beta, normed);
    so3lin_out<<<gLin, 128, 0, stream>>>(normed, Wo, bo, out);
}

// Round 2
// 205.165 us; speedup vs baseline: 1.9114x; 1.9114x over previous
//
#include <hip/hip_runtime.h>
#include <hip/hip_bf16.h>
#include <math.h>

#define NH 8
#define SDIM 9
#define NSEG 16
#define NATOM 512
#define NEDGE 8192
#define CIN 128
#define CHN 256
#define DH 32
#define FDIM 288            // SDIM*DH
#define EPS 1e-7f
#define SCALE 0.10206207261596577f   // sqrt(32/3)/32

// ---------------- block reduce helpers (blockDim.x == 256) ----------------
__device__ inline float blockReduceMax(float v, float* red) {
    #pragma unroll
    for (int off = 32; off; off >>= 1) v = fmaxf(v, __shfl_xor(v, off, 64));
    int lane = threadIdx.x & 63, wid = threadIdx.x >> 6;
    if (lane == 0) red[wid] = v;
    __syncthreads();
    v = fmaxf(fmaxf(red[0], red[1]), fmaxf(red[2], red[3]));
    __syncthreads();
    return v;
}
__device__ inline float blockReduceSum(float v, float* red) {
    #pragma unroll
    for (int off = 32; off; off >>= 1) v += __shfl_xor(v, off, 64);
    int lane = threadIdx.x & 63, wid = threadIdx.x >> 6;
    if (lane == 0) red[wid] = v;
    __syncthreads();
    v = red[0] + red[1] + red[2] + red[3];
    __syncthreads();
    return v;
}

// ---------------- K0a: segment starts from sorted batch_index ----------------
__global__ void seg_start(const int* __restrict__ batch, int* __restrict__ segStart) {
    int e = blockIdx.x * 256 + threadIdx.x;
    if (e >= NEDGE) return;
    int b = batch[e];
    if (e == 0) {
        for (int s2 = 0; s2 <= b; ++s2) segStart[s2] = 0;
    } else {
        int bp = batch[e - 1];
        for (int s2 = bp + 1; s2 <= b; ++s2) segStart[s2] = e;
    }
    if (e == NEDGE - 1) {
        for (int s2 = b + 1; s2 <= NSEG; ++s2) segStart[s2] = NEDGE;
    }
}

// ---------------- K0b: per-head max bias (any upper bound works; shift cancels) ----------------
__global__ void __launch_bounds__(256) head_maxbias(const float* __restrict__ attn_bias,
                                                    float* __restrict__ maxB) {
    const int h = blockIdx.x;
    __shared__ float red[4];
    float v = -1e30f;
    for (int e = threadIdx.x; e < NEDGE; e += 256)
        v = fmaxf(v, attn_bias[(size_t)h * NEDGE + e]);
    v = blockReduceMax(v, red);
    if (threadIdx.x == 0) maxB[h] = v;
}

// ---------------- K0c: collapse edges -> per-(h,seg,atom) tables E1,E2 ----------------
// E1[h,seg,m] = sum_{e in seg, am[e]=m} env[e]   * exp(bias[h,e]-maxB[h])
// E2[h,seg,m] = sum_{e in seg, am[e]=m} env[e]^2 * exp(bias[h,e]-maxB[h])
__global__ void __launch_bounds__(256) seg_tables(const int* __restrict__ am, const int* __restrict__ emap,
                                                  const float* __restrict__ envelope,
                                                  const float* __restrict__ attn_bias,
                                                  const int* __restrict__ segStart,
                                                  const float* __restrict__ maxB,
                                                  float* __restrict__ E1, float* __restrict__ E2) {
    const int seg = blockIdx.x, h = blockIdx.y;
    __shared__ float e1[NATOM];
    __shared__ float e2[NATOM];
    const int tid = threadIdx.x;
    e1[tid] = 0.f; e1[tid + 256] = 0.f;
    e2[tid] = 0.f; e2[tid + 256] = 0.f;
    __syncthreads();
    const int st = segStart[seg], en = segStart[seg + 1];
    const float mb = maxB[h];
    for (int e = st + tid; e < en; e += 256) {
        int m = am[e], em = emap[e];
        float ev = envelope[em];
        float eb = __expf(attn_bias[(size_t)h * NEDGE + em] - mb);
        atomicAdd(&e1[m], ev * eb);
        atomicAdd(&e2[m], ev * ev * eb);
    }
    __syncthreads();
    size_t base = ((size_t)h * NSEG + seg) * NATOM;
    E1[base + tid] = e1[tid]; E1[base + tid + 256] = e1[tid + 256];
    E2[base + tid] = e2[tid]; E2[base + tid + 256] = e2[tid + 256];
}

// ---------------- K1: so3_linear (CIN=128 -> CHN=256), write (H,N,F) layout ----------------
__global__ void __launch_bounds__(256) so3lin_in(const float* __restrict__ x, const float* __restrict__ W,
                                                const float* __restrict__ b, float* __restrict__ out) {
    const int n0 = blockIdx.x * 8;
    const int s = blockIdx.y;
    const int l = (s == 0) ? 0 : ((s < 4) ? 1 : 2);
    __shared__ float xs[8][CIN];
    const int tid = threadIdx.x;
    for (int idx = tid; idx < 8 * CIN; idx += 256) {
        int r = idx >> 7, i = idx & 127;
        xs[r][i] = x[((size_t)(n0 + r) * SDIM + s) * CIN + i];
    }
    __syncthreads();
    const int o = tid;
    const float* Wl = W + (size_t)l * CIN * CHN + o;
    float acc[8] = {0, 0, 0, 0, 0, 0, 0, 0};
    #pragma unroll 4
    for (int i = 0; i < CIN; ++i) {
        float w = Wl[(size_t)i * CHN];
        #pragma unroll
        for (int r = 0; r < 8; ++r) acc[r] += xs[r][i] * w;
    }
    float bb = (s == 0) ? b[o] : 0.f;
    const int h = o >> 5, dj = o & 31;
    #pragma unroll
    for (int r = 0; r < 8; ++r)
        out[((size_t)h * NATOM + (n0 + r)) * FDIM + s * DH + dj] = acc[r] + bb;
}

// ---------------- K2: scoresA[h][n][m] = SCALE * dot(qh[h,n,:], kh[h,m,:]) ----------------
__global__ void __launch_bounds__(256) gemm_scores(const float* __restrict__ qh, const float* __restrict__ kh,
                                                   float* __restrict__ scoresA) {
    const int h = blockIdx.z;
    const int m0 = blockIdx.x * 64;
    const int n0 = blockIdx.y * 64;
    const float* A = qh + (size_t)h * NATOM * FDIM;
    const float* B = kh + (size_t)h * NATOM * FDIM;
    __shared__ float As[64][17];
    __shared__ float Bs[64][17];
    const int tid = threadIdx.x;
    const int tx = tid & 15, ty = tid >> 4;
    const int lr = tid >> 2;
    const int lc = (tid & 3) << 2;
    float acc[4][4] = {};
    for (int kk = 0; kk < FDIM; kk += 16) {
        float4 a4 = *(const float4*)(A + (size_t)(n0 + lr) * FDIM + kk + lc);
        float4 b4 = *(const float4*)(B + (size_t)(m0 + lr) * FDIM + kk + lc);
        As[lr][lc + 0] = a4.x; As[lr][lc + 1] = a4.y; As[lr][lc + 2] = a4.z; As[lr][lc + 3] = a4.w;
        Bs[lr][lc + 0] = b4.x; Bs[lr][lc + 1] = b4.y; Bs[lr][lc + 2] = b4.z; Bs[lr][lc + 3] = b4.w;
        __syncthreads();
        #pragma unroll
        for (int k2 = 0; k2 < 16; ++k2) {
            float a[4], b[4];
            #pragma unroll
            for (int i = 0; i < 4; ++i) a[i] = As[ty * 4 + i][k2];
            #pragma unroll
            for (int j = 0; j < 4; ++j) b[j] = Bs[tx * 4 + j][k2];
            #pragma unroll
            for (int i = 0; i < 4; ++i)
                #pragma unroll
                for (int j = 0; j < 4; ++j) acc[i][j] += a[i] * b[j];
        }
        __syncthreads();
    }
    #pragma unroll
    for (int i = 0; i < 4; ++i) {
        size_t rowo = ((size_t)h * NATOM + n0 + ty * 4 + i) * NATOM + m0 + tx * 4;
        #pragma unroll
        for (int j = 0; j < 4; ++j) scoresA[rowo + j] = acc[i][j] * SCALE;
    }
}

// ---------------- K3: collapsed segmented softmax (in-place on scoresA) ----------------
// attnA[h,n,m] = es[m] * sum_seg E2[h,seg,m] / (sum_m' es[m']*E1[h,seg,m'] + 1e-30)
// where es[m] = exp(s[n,m] - rowmax). All shifts cancel exactly.
#define SM_ROWS 8
__global__ void __launch_bounds__(256) softmax_agg2(float* __restrict__ scoresA,
                                                    const float* __restrict__ E1,
                                                    const float* __restrict__ E2) {
    const int h = blockIdx.y;
    const int n0 = blockIdx.x * SM_ROWS;
    __shared__ float E1s[NSEG][NATOM];   // 32 KB
    __shared__ float E2s[NSEG][NATOM];   // 32 KB
    __shared__ float redw[4];
    __shared__ float redD[4][NSEG];
    __shared__ float invDs[NSEG];
    const int tid = threadIdx.x;
    const int lane = tid & 63, wid = tid >> 6;
    const float* e1g = E1 + (size_t)h * NSEG * NATOM;
    const float* e2g = E2 + (size_t)h * NSEG * NATOM;
    for (int i = tid * 4; i < NSEG * NATOM; i += 1024) {
        *(float4*)&((float*)E1s)[i] = *(const float4*)&e1g[i];
        *(float4*)&((float*)E2s)[i] = *(const float4*)&e2g[i];
    }
    __syncthreads();
    for (int r = 0; r < SM_ROWS; ++r) {
        float* srow = scoresA + ((size_t)h * NATOM + n0 + r) * NATOM;
        float s1 = srow[tid], s2 = srow[tid + 256];
        float R = blockReduceMax(fmaxf(s1, s2), redw);
        float es1 = __expf(s1 - R), es2 = __expf(s2 - R);
        float D[NSEG];
        #pragma unroll
        for (int g = 0; g < NSEG; ++g)
            D[g] = es1 * E1s[g][tid] + es2 * E1s[g][tid + 256];
        #pragma unroll
        for (int g = 0; g < NSEG; ++g) {
            float vsum = D[g];
            #pragma unroll
            for (int off = 32; off; off >>= 1) vsum += __shfl_xor(vsum, off, 64);
            if (lane == 0) redD[wid][g] = vsum;
        }
        __syncthreads();
        if (tid < NSEG)
            invDs[tid] = 1.0f / (redD[0][tid] + redD[1][tid] + redD[2][tid] + redD[3][tid] + 1e-30f);
        __syncthreads();
        float w1 = 0.f, w2 = 0.f;
        #pragma unroll
        for (int g = 0; g < NSEG; ++g) {
            float iv = invDs[g];
            w1 += E2s[g][tid] * iv;
            w2 += E2s[g][tid + 256] * iv;
        }
        srow[tid] = es1 * w1;
        srow[tid + 256] = es2 * w2;
        __syncthreads();
    }
}

// ---------------- K4: attnOut[n][s][h*32+dj] = sum_m attnA[h,n,m]*vh[h,m,f], f=s*32+dj ----------------
__global__ void __launch_bounds__(256) gemm_out(const float* __restrict__ attnA, const float* __restrict__ vh,
                                                float* __restrict__ attnOut) {
    const int h = blockIdx.z;
    const int f0 = blockIdx.x * 64;
    const int n0 = blockIdx.y * 64;
    const float* A = attnA + (size_t)h * NATOM * NATOM;
    const float* B = vh + (size_t)h * NATOM * FDIM;
    __shared__ float As[64][17];
    __shared__ float Bs[16][68];
    const int tid = threadIdx.x;
    const int tx = tid & 15, ty = tid >> 4;
    const int ar = tid >> 2, ac = (tid & 3) << 2;
    const int bk_ = tid >> 4, bc = (tid & 15) << 2;
    const bool bok = (f0 + bc) < FDIM;
    float acc[4][4] = {};
    for (int kk = 0; kk < NATOM; kk += 16) {
        float4 a4 = *(const float4*)(A + (size_t)(n0 + ar) * NATOM + kk + ac);
        As[ar][ac + 0] = a4.x; As[ar][ac + 1] = a4.y; As[ar][ac + 2] = a4.z; As[ar][ac + 3] = a4.w;
        if (bok) {
            float4 b4 = *(const float4*)(B + (size_t)(kk + bk_) * FDIM + f0 + bc);
            Bs[bk_][bc + 0] = b4.x; Bs[bk_][bc + 1] = b4.y; Bs[bk_][bc + 2] = b4.z; Bs[bk_][bc + 3] = b4.w;
        } else {
            Bs[bk_][bc + 0] = 0.f; Bs[bk_][bc + 1] = 0.f; Bs[bk_][bc + 2] = 0.f; Bs[bk_][bc + 3] = 0.f;
        }
        __syncthreads();
        #pragma unroll
        for (int k2 = 0; k2 < 16; ++k2) {
            float4 b4 = *(const float4*)(&Bs[k2][tx * 4]);
            float a[4];
            #pragma unroll
            for (int i = 0; i < 4; ++i) a[i] = As[ty * 4 + i][k2];
            #pragma unroll
            for (int i = 0; i < 4; ++i) {
                acc[i][0] += a[i] * b4.x;
                acc[i][1] += a[i] * b4.y;
                acc[i][2] += a[i] * b4.z;
                acc[i][3] += a[i] * b4.w;
            }
        }
        __syncthreads();
    }
    #pragma unroll
    for (int i = 0; i < 4; ++i) {
        int n = n0 + ty * 4 + i;
        #pragma unroll
        for (int j = 0; j < 4; ++j) {
            int f = f0 + tx * 4 + j;
            if (f < FDIM) {
                int s = f >> 5, dj = f & 31;
                attnOut[((size_t)n * SDIM + s) * CHN + h * DH + dj] = acc[i][j];
            }
        }
    }
}

// ---------------- K5: equivariant layernorm ----------------
__global__ void __launch_bounds__(256) eqln(const float* __restrict__ xin, const float* __restrict__ gamma,
                                            const float* __restrict__ beta, float* __restrict__ outn) {
    const int n = blockIdx.x;
    const int c = threadIdx.x;
    __shared__ float red[4];
    float xv[SDIM];
    #pragma unroll
    for (int s = 0; s < SDIM; ++s) xv[s] = xin[((size_t)n * SDIM + s) * CHN + c];
    // l = 0
    float mu = blockReduceSum(xv[0], red) * (1.0f / CHN);
    float dv = xv[0] - mu;
    float var = blockReduceSum(dv * dv, red) * (1.0f / CHN);
    float y0 = dv / sqrtf(var + EPS) * gamma[c] + beta[c];
    outn[(size_t)n * SDIM * CHN + c] = y0;
    // l = 1 (rows 1..3)
    float n2 = (xv[1] * xv[1] + xv[2] * xv[2] + xv[3] * xv[3]) * (1.0f / 3.0f);
    float ms = blockReduceSum(n2, red) * (1.0f / CHN);
    float inv1 = 1.0f / sqrtf(ms + EPS);
    #pragma unroll
    for (int s = 1; s < 4; ++s)
        outn[((size_t)n * SDIM + s) * CHN + c] = xv[s] * inv1 * gamma[CHN + c];
    // l = 2 (rows 4..8)
    float n22 = (xv[4] * xv[4] + xv[5] * xv[5] + xv[6] * xv[6] + xv[7] * xv[7] + xv[8] * xv[8]) * (1.0f / 5.0f);
    float ms2 = blockReduceSum(n22, red) * (1.0f / CHN);
    float inv2 = 1.0f / sqrtf(ms2 + EPS);
    #pragma unroll
    for (int s = 4; s < SDIM; ++s)
        outn[((size_t)n * SDIM + s) * CHN + c] = xv[s] * inv2 * gamma[2 * CHN + c];
}

// ---------------- K6: final so3_linear (CHN=256 -> CIN=128) ----------------
__global__ void __launch_bounds__(128) so3lin_out(const float* __restrict__ xn, const float* __restrict__ Wo,
                                                  const float* __restrict__ bo, float* __restrict__ out) {
    const int n0 = blockIdx.x * 8;
    const int s = blockIdx.y;
    const int l = (s == 0) ? 0 : ((s < 4) ? 1 : 2);
    __shared__ float xs[8][CHN];
    const int tid = threadIdx.x;
    for (int idx = tid; idx < 8 * CHN; idx += 128) {
        int r = idx >> 8, i = idx & 255;
        xs[r][i] = xn[((size_t)(n0 + r) * SDIM + s) * CHN + i];
    }
    __syncthreads();
    const int o = tid;
    const float* Wl = Wo + (size_t)l * CHN * CIN + o;
    float acc[8] = {0, 0, 0, 0, 0, 0, 0, 0};
    #pragma unroll 4
    for (int i = 0; i < CHN; ++i) {
        float w = Wl[(size_t)i * CIN];
        #pragma unroll
        for (int r = 0; r < 8; ++r) acc[r] += xs[r][i] * w;
    }
    float bb = (s == 0) ? bo[o] : 0.f;
    #pragma unroll
    for (int r = 0; r < 8; ++r)
        out[((size_t)(n0 + r) * SDIM + s) * CIN + o] = acc[r] + bb;
}

extern "C" void kernel_launch(void* const* d_in, const int* in_sizes, int n_in,
                              void* d_out, int out_size, void* d_ws, size_t ws_size,
                              hipStream_t stream) {
    const float* q = (const float*)d_in[0];
    const float* k = (const float*)d_in[1];
    const float* v = (const float*)d_in[2];
    const float* envelope = (const float*)d_in[3];
    const float* attn_bias = (const float*)d_in[4];
    const int* atom_index = (const int*)d_in[5];
    const int* batch_index = (const int*)d_in[6];
    const int* edge_map = (const int*)d_in[7];
    const float* Wq = (const float*)d_in[8];
    const float* bq = (const float*)d_in[9];
    const float* Wk = (const float*)d_in[10];
    const float* bk = (const float*)d_in[11];
    const float* Wv = (const float*)d_in[12];
    const float* bv = (const float*)d_in[13];
    const float* gamma = (const float*)d_in[14];
    const float* beta = (const float*)d_in[15];
    const float* Wo = (const float*)d_in[16];
    const float* bo = (const float*)d_in[17];
    float* out = (float*)d_out;

    const size_t SZ_HNF = (size_t)NH * NATOM * FDIM;      // 1179648
    const size_t SZ_HNN = (size_t)NH * NATOM * NATOM;     // 2097152
    const size_t SZ_TAB = (size_t)NH * NSEG * NATOM;      // 65536
    float* ws = (float*)d_ws;
    float* qh = ws;
    float* kh = qh + SZ_HNF;
    float* vh = kh + SZ_HNF;
    float* scoresA = vh + SZ_HNF;            // also attnA (in-place)
    float* E1 = scoresA + SZ_HNN;
    float* E2 = E1 + SZ_TAB;
    float* maxB = E2 + SZ_TAB;
    int* segStart = (int*)(maxB + 16);
    float* attnOut = kh;                      // reuse after gemm_scores
    float* normed = qh;                       // reuse after gemm_scores

    size_t needed = (3 * SZ_HNF + SZ_HNN + 2 * SZ_TAB + 64) * 4;
    if (ws_size < needed) return;

    seg_start<<<NEDGE / 256, 256, 0, stream>>>(batch_index, segStart);
    head_maxbias<<<NH, 256, 0, stream>>>(attn_bias, maxB);
    dim3 gLin(NATOM / 8, SDIM);
    so3lin_in<<<gLin, 256, 0, stream>>>(q, Wq, bq, qh);
    so3lin_in<<<gLin, 256, 0, stream>>>(k, Wk, bk, kh);
    so3lin_in<<<gLin, 256, 0, stream>>>(v, Wv, bv, vh);
    seg_tables<<<dim3(NSEG, NH), 256, 0, stream>>>(atom_index, edge_map, envelope, attn_bias,
                                                   segStart, maxB, E1, E2);
    gemm_scores<<<dim3(NATOM / 64, NATOM / 64, NH), 256, 0, stream>>>(qh, kh, scoresA);
    softmax_agg2<<<dim3(NATOM / SM_ROWS, NH), 256, 0, stream>>>(scoresA, E1, E2);
    gemm_out<<<dim3((FDIM + 63) / 64, NATOM / 64, NH), 256, 0, stream>>>(scoresA, vh, attnOut);
    eqln<<<NATOM, 256, 0, stream>>>(attnOut, gamma, beta, normed);
    so3lin_out<<<gLin, 128, 0, stream>>>(normed, Wo, bo, out);
}

// Round 3
// 148.107 us; speedup vs baseline: 2.6478x; 1.3853x over previous
//
#include <hip/hip_runtime.h>
#include <hip/hip_bf16.h>
#include <math.h>

#define NH 8
#define SDIM 9
#define NSEG 16
#define NATOM 512
#define NEDGE 8192
#define CIN 128
#define CHN 256
#define DH 32
#define FDIM 288            // SDIM*DH
#define EPS 1e-7f
#define SCALE 0.10206207261596577f   // sqrt(32/3)/32

typedef __attribute__((ext_vector_type(8))) short bf16x8;
typedef __attribute__((ext_vector_type(4))) float f32x4;

// ---------------- block reduce helpers (blockDim.x == 256) ----------------
__device__ inline float blockReduceMax(float v, float* red) {
    #pragma unroll
    for (int off = 32; off; off >>= 1) v = fmaxf(v, __shfl_xor(v, off, 64));
    int lane = threadIdx.x & 63, wid = threadIdx.x >> 6;
    if (lane == 0) red[wid] = v;
    __syncthreads();
    v = fmaxf(fmaxf(red[0], red[1]), fmaxf(red[2], red[3]));
    __syncthreads();
    return v;
}
__device__ inline float blockReduceSum(float v, float* red) {
    #pragma unroll
    for (int off = 32; off; off >>= 1) v += __shfl_xor(v, off, 64);
    int lane = threadIdx.x & 63, wid = threadIdx.x >> 6;
    if (lane == 0) red[wid] = v;
    __syncthreads();
    v = red[0] + red[1] + red[2] + red[3];
    __syncthreads();
    return v;
}

// ---------------- K0a: segment starts from sorted batch_index ----------------
__global__ void seg_start(const int* __restrict__ batch, int* __restrict__ segStart) {
    int e = blockIdx.x * 256 + threadIdx.x;
    if (e >= NEDGE) return;
    int b = batch[e];
    if (e == 0) {
        for (int s2 = 0; s2 <= b; ++s2) segStart[s2] = 0;
    } else {
        int bp = batch[e - 1];
        for (int s2 = bp + 1; s2 <= b; ++s2) segStart[s2] = e;
    }
    if (e == NEDGE - 1) {
        for (int s2 = b + 1; s2 <= NSEG; ++s2) segStart[s2] = NEDGE;
    }
}

// ---------------- K0b: per-head max bias ----------------
__global__ void __launch_bounds__(256) head_maxbias(const float* __restrict__ attn_bias,
                                                    float* __restrict__ maxB) {
    const int h = blockIdx.x;
    __shared__ float red[4];
    float v = -1e30f;
    for (int e = threadIdx.x; e < NEDGE; e += 256)
        v = fmaxf(v, attn_bias[(size_t)h * NEDGE + e]);
    v = blockReduceMax(v, red);
    if (threadIdx.x == 0) maxB[h] = v;
}

// ---------------- K0c: collapse edges -> per-(h,seg,atom) tables E1,E2 ----------------
__global__ void __launch_bounds__(256) seg_tables(const int* __restrict__ am, const int* __restrict__ emap,
                                                  const float* __restrict__ envelope,
                                                  const float* __restrict__ attn_bias,
                                                  const int* __restrict__ segStart,
                                                  const float* __restrict__ maxB,
                                                  float* __restrict__ E1, float* __restrict__ E2) {
    const int seg = blockIdx.x, h = blockIdx.y;
    __shared__ float e1[NATOM];
    __shared__ float e2[NATOM];
    const int tid = threadIdx.x;
    e1[tid] = 0.f; e1[tid + 256] = 0.f;
    e2[tid] = 0.f; e2[tid + 256] = 0.f;
    __syncthreads();
    const int st = segStart[seg], en = segStart[seg + 1];
    const float mb = maxB[h];
    for (int e = st + tid; e < en; e += 256) {
        int m = am[e], em = emap[e];
        float ev = envelope[em];
        float eb = __expf(attn_bias[(size_t)h * NEDGE + em] - mb);
        atomicAdd(&e1[m], ev * eb);
        atomicAdd(&e2[m], ev * ev * eb);
    }
    __syncthreads();
    size_t base = ((size_t)h * NSEG + seg) * NATOM;
    E1[base + tid] = e1[tid]; E1[base + tid + 256] = e1[tid + 256];
    E2[base + tid] = e2[tid]; E2[base + tid + 256] = e2[tid + 256];
}

// ---------------- K1a: so3_linear -> bf16 (H,N,F), optional pre-scale ----------------
__global__ void __launch_bounds__(256) so3lin_in_qk(const float* __restrict__ x, const float* __restrict__ W,
                                                    const float* __restrict__ b, __hip_bfloat16* __restrict__ out,
                                                    float scale) {
    const int n0 = blockIdx.x * 8;
    const int s = blockIdx.y;
    const int l = (s == 0) ? 0 : ((s < 4) ? 1 : 2);
    __shared__ float xs[8][CIN];
    const int tid = threadIdx.x;
    for (int idx = tid; idx < 8 * CIN; idx += 256) {
        int r = idx >> 7, i = idx & 127;
        xs[r][i] = x[((size_t)(n0 + r) * SDIM + s) * CIN + i];
    }
    __syncthreads();
    const int o = tid;
    const float* Wl = W + (size_t)l * CIN * CHN + o;
    float acc[8] = {0, 0, 0, 0, 0, 0, 0, 0};
    #pragma unroll 4
    for (int i = 0; i < CIN; ++i) {
        float w = Wl[(size_t)i * CHN];
        #pragma unroll
        for (int r = 0; r < 8; ++r) acc[r] += xs[r][i] * w;
    }
    float bb = (s == 0) ? b[o] : 0.f;
    const int h = o >> 5, dj = o & 31;
    #pragma unroll
    for (int r = 0; r < 8; ++r)
        out[((size_t)h * NATOM + (n0 + r)) * FDIM + s * DH + dj] = __float2bfloat16((acc[r] + bb) * scale);
}

// ---------------- K1b: so3_linear for V -> bf16 transposed (H,F,N) ----------------
__global__ void __launch_bounds__(256) so3lin_in_vT(const float* __restrict__ x, const float* __restrict__ W,
                                                    const float* __restrict__ b, __hip_bfloat16* __restrict__ outT) {
    const int n0 = blockIdx.x * 8;
    const int s = blockIdx.y;
    const int l = (s == 0) ? 0 : ((s < 4) ? 1 : 2);
    __shared__ float xs[8][CIN];
    const int tid = threadIdx.x;
    for (int idx = tid; idx < 8 * CIN; idx += 256) {
        int r = idx >> 7, i = idx & 127;
        xs[r][i] = x[((size_t)(n0 + r) * SDIM + s) * CIN + i];
    }
    __syncthreads();
    const int o = tid;
    const float* Wl = W + (size_t)l * CIN * CHN + o;
    float acc[8] = {0, 0, 0, 0, 0, 0, 0, 0};
    #pragma unroll 4
    for (int i = 0; i < CIN; ++i) {
        float w = Wl[(size_t)i * CHN];
        #pragma unroll
        for (int r = 0; r < 8; ++r) acc[r] += xs[r][i] * w;
    }
    float bb = (s == 0) ? b[o] : 0.f;
    const int h = o >> 5, dj = o & 31;
    const int f = s * DH + dj;
    __hip_bfloat16* dst = outT + ((size_t)h * FDIM + f) * NATOM + n0;
    #pragma unroll
    for (int r = 0; r < 8; ++r) dst[r] = __float2bfloat16(acc[r] + bb);
}

// ---------------- K2: MFMA scores: scoresA[h][n][m] = dot(qhB[h,n,:], khB[h,m,:]) ----------------
__global__ void __launch_bounds__(256) gemm_scores_mfma(const ushort* __restrict__ qhB,
                                                        const ushort* __restrict__ khB,
                                                        float* __restrict__ scoresA) {
    const int h = blockIdx.z;
    const int m0 = blockIdx.x * 64;
    const int n0 = blockIdx.y * 64;
    const int tid = threadIdx.x;
    const int lane = tid & 63, w = tid >> 6;
    const int wr = w >> 1, wc = w & 1;
    const int r = lane & 15, kg = lane >> 4;
    const ushort* A = qhB + (size_t)h * NATOM * FDIM;
    const ushort* B = khB + (size_t)h * NATOM * FDIM;
    const int ar = n0 + 32 * wr + r;
    const int br = m0 + 32 * wc + r;
    f32x4 acc00 = {}, acc01 = {}, acc10 = {}, acc11 = {};
    #pragma unroll
    for (int ks = 0; ks < FDIM / 32; ++ks) {
        const int k0 = ks * 32 + kg * 8;
        bf16x8 a0 = *(const bf16x8*)(A + (size_t)ar * FDIM + k0);
        bf16x8 a1 = *(const bf16x8*)(A + (size_t)(ar + 16) * FDIM + k0);
        bf16x8 b0 = *(const bf16x8*)(B + (size_t)br * FDIM + k0);
        bf16x8 b1 = *(const bf16x8*)(B + (size_t)(br + 16) * FDIM + k0);
        acc00 = __builtin_amdgcn_mfma_f32_16x16x32_bf16(a0, b0, acc00, 0, 0, 0);
        acc01 = __builtin_amdgcn_mfma_f32_16x16x32_bf16(a0, b1, acc01, 0, 0, 0);
        acc10 = __builtin_amdgcn_mfma_f32_16x16x32_bf16(a1, b0, acc10, 0, 0, 0);
        acc11 = __builtin_amdgcn_mfma_f32_16x16x32_bf16(a1, b1, acc11, 0, 0, 0);
    }
    #define STORE_SC(ACC, I, J) { \
        int row = n0 + 32 * wr + (I) * 16 + kg * 4; \
        int col = m0 + 32 * wc + (J) * 16 + r; \
        float* dst = scoresA + ((size_t)h * NATOM + row) * NATOM + col; \
        dst[0] = ACC[0]; dst[NATOM] = ACC[1]; dst[2 * NATOM] = ACC[2]; dst[3 * NATOM] = ACC[3]; }
    STORE_SC(acc00, 0, 0) STORE_SC(acc01, 0, 1) STORE_SC(acc10, 1, 0) STORE_SC(acc11, 1, 1)
    #undef STORE_SC
}

// ---------------- K3: collapsed segmented softmax (scoresA fp32 -> attnB bf16) ----------------
#define SM_ROWS 8
__global__ void __launch_bounds__(256) softmax_agg2(const float* __restrict__ scoresA,
                                                    __hip_bfloat16* __restrict__ attnB,
                                                    const float* __restrict__ E1,
                                                    const float* __restrict__ E2) {
    const int h = blockIdx.y;
    const int n0 = blockIdx.x * SM_ROWS;
    __shared__ float E1s[NSEG][NATOM];   // 32 KB
    __shared__ float E2s[NSEG][NATOM];   // 32 KB
    __shared__ float redw[4];
    __shared__ float redD[4][NSEG];
    __shared__ float invDs[NSEG];
    const int tid = threadIdx.x;
    const int lane = tid & 63, wid = tid >> 6;
    const float* e1g = E1 + (size_t)h * NSEG * NATOM;
    const float* e2g = E2 + (size_t)h * NSEG * NATOM;
    for (int i = tid * 4; i < NSEG * NATOM; i += 1024) {
        *(float4*)&((float*)E1s)[i] = *(const float4*)&e1g[i];
        *(float4*)&((float*)E2s)[i] = *(const float4*)&e2g[i];
    }
    __syncthreads();
    for (int r = 0; r < SM_ROWS; ++r) {
        const float* srow = scoresA + ((size_t)h * NATOM + n0 + r) * NATOM;
        float s1 = srow[tid], s2 = srow[tid + 256];
        float R = blockReduceMax(fmaxf(s1, s2), redw);
        float es1 = __expf(s1 - R), es2 = __expf(s2 - R);
        float D[NSEG];
        #pragma unroll
        for (int g = 0; g < NSEG; ++g)
            D[g] = es1 * E1s[g][tid] + es2 * E1s[g][tid + 256];
        #pragma unroll
        for (int g = 0; g < NSEG; ++g) {
            float vsum = D[g];
            #pragma unroll
            for (int off = 32; off; off >>= 1) vsum += __shfl_xor(vsum, off, 64);
            if (lane == 0) redD[wid][g] = vsum;
        }
        __syncthreads();
        if (tid < NSEG)
            invDs[tid] = 1.0f / (redD[0][tid] + redD[1][tid] + redD[2][tid] + redD[3][tid] + 1e-30f);
        __syncthreads();
        float w1 = 0.f, w2 = 0.f;
        #pragma unroll
        for (int g = 0; g < NSEG; ++g) {
            float iv = invDs[g];
            w1 += E2s[g][tid] * iv;
            w2 += E2s[g][tid + 256] * iv;
        }
        __hip_bfloat16* arow = attnB + ((size_t)h * NATOM + n0 + r) * NATOM;
        arow[tid] = __float2bfloat16(es1 * w1);
        arow[tid + 256] = __float2bfloat16(es2 * w2);
        __syncthreads();
    }
}

// ---------------- K4: MFMA out: attnOut[n][s][h*32+dj] = sum_m attnB[h,n,m]*vhT[h,f,m] ----------------
__global__ void __launch_bounds__(256) gemm_out_mfma(const ushort* __restrict__ attnB,
                                                     const ushort* __restrict__ vhT,
                                                     float* __restrict__ attnOut) {
    const int h = blockIdx.z;
    const int f0 = blockIdx.x * 64;
    const int n0 = blockIdx.y * 64;
    const int tid = threadIdx.x;
    const int lane = tid & 63, w = tid >> 6;
    const int wr = w >> 1, wc = w & 1;
    const int r = lane & 15, kg = lane >> 4;
    const ushort* A = attnB + (size_t)h * NATOM * NATOM;
    const ushort* B = vhT + (size_t)h * FDIM * NATOM;
    const int ar = n0 + 32 * wr + r;
    const int br = f0 + 32 * wc + r;
    const bool b0ok = (f0 + 32 * wc) < FDIM;        // wave-uniform row-block validity
    const bool b1ok = (f0 + 32 * wc + 16) < FDIM;
    f32x4 acc00 = {}, acc01 = {}, acc10 = {}, acc11 = {};
    const bf16x8 bz = {};
    #pragma unroll 4
    for (int ks = 0; ks < NATOM / 32; ++ks) {
        const int k0 = ks * 32 + kg * 8;
        bf16x8 a0 = *(const bf16x8*)(A + (size_t)ar * NATOM + k0);
        bf16x8 a1 = *(const bf16x8*)(A + (size_t)(ar + 16) * NATOM + k0);
        bf16x8 b0 = b0ok ? *(const bf16x8*)(B + (size_t)br * NATOM + k0) : bz;
        bf16x8 b1 = b1ok ? *(const bf16x8*)(B + (size_t)(br + 16) * NATOM + k0) : bz;
        acc00 = __builtin_amdgcn_mfma_f32_16x16x32_bf16(a0, b0, acc00, 0, 0, 0);
        acc01 = __builtin_amdgcn_mfma_f32_16x16x32_bf16(a0, b1, acc01, 0, 0, 0);
        acc10 = __builtin_amdgcn_mfma_f32_16x16x32_bf16(a1, b0, acc10, 0, 0, 0);
        acc11 = __builtin_amdgcn_mfma_f32_16x16x32_bf16(a1, b1, acc11, 0, 0, 0);
    }
    #define STORE_OUT(ACC, I, J) { \
        int row = n0 + 32 * wr + (I) * 16 + kg * 4; \
        int f = f0 + 32 * wc + (J) * 16 + r; \
        if (f < FDIM) { \
            int s = f >> 5, dj = f & 31; \
            float* dst = attnOut + ((size_t)row * SDIM + s) * CHN + h * DH + dj; \
            dst[0] = ACC[0]; dst[SDIM * CHN] = ACC[1]; dst[2 * SDIM * CHN] = ACC[2]; dst[3 * SDIM * CHN] = ACC[3]; } }
    STORE_OUT(acc00, 0, 0) STORE_OUT(acc01, 0, 1) STORE_OUT(acc10, 1, 0) STORE_OUT(acc11, 1, 1)
    #undef STORE_OUT
}

// ---------------- K5: equivariant layernorm ----------------
__global__ void __launch_bounds__(256) eqln(const float* __restrict__ xin, const float* __restrict__ gamma,
                                            const float* __restrict__ beta, float* __restrict__ outn) {
    const int n = blockIdx.x;
    const int c = threadIdx.x;
    __shared__ float red[4];
    float xv[SDIM];
    #pragma unroll
    for (int s = 0; s < SDIM; ++s) xv[s] = xin[((size_t)n * SDIM + s) * CHN + c];
    float mu = blockReduceSum(xv[0], red) * (1.0f / CHN);
    float dv = xv[0] - mu;
    float var = blockReduceSum(dv * dv, red) * (1.0f / CHN);
    float y0 = dv / sqrtf(var + EPS) * gamma[c] + beta[c];
    outn[(size_t)n * SDIM * CHN + c] = y0;
    float n2 = (xv[1] * xv[1] + xv[2] * xv[2] + xv[3] * xv[3]) * (1.0f / 3.0f);
    float ms = blockReduceSum(n2, red) * (1.0f / CHN);
    float inv1 = 1.0f / sqrtf(ms + EPS);
    #pragma unroll
    for (int s = 1; s < 4; ++s)
        outn[((size_t)n * SDIM + s) * CHN + c] = xv[s] * inv1 * gamma[CHN + c];
    float n22 = (xv[4] * xv[4] + xv[5] * xv[5] + xv[6] * xv[6] + xv[7] * xv[7] + xv[8] * xv[8]) * (1.0f / 5.0f);
    float ms2 = blockReduceSum(n22, red) * (1.0f / CHN);
    float inv2 = 1.0f / sqrtf(ms2 + EPS);
    #pragma unroll
    for (int s = 4; s < SDIM; ++s)
        outn[((size_t)n * SDIM + s) * CHN + c] = xv[s] * inv2 * gamma[2 * CHN + c];
}

// ---------------- K6: final so3_linear (CHN=256 -> CIN=128) ----------------
__global__ void __launch_bounds__(128) so3lin_out(const float* __restrict__ xn, const float* __restrict__ Wo,
                                                  const float* __restrict__ bo, float* __restrict__ out) {
    const int n0 = blockIdx.x * 8;
    const int s = blockIdx.y;
    const int l = (s == 0) ? 0 : ((s < 4) ? 1 : 2);
    __shared__ float xs[8][CHN];
    const int tid = threadIdx.x;
    for (int idx = tid; idx < 8 * CHN; idx += 128) {
        int r = idx >> 8, i = idx & 255;
        xs[r][i] = xn[((size_t)(n0 + r) * SDIM + s) * CHN + i];
    }
    __syncthreads();
    const int o = tid;
    const float* Wl = Wo + (size_t)l * CHN * CIN + o;
    float acc[8] = {0, 0, 0, 0, 0, 0, 0, 0};
    #pragma unroll 4
    for (int i = 0; i < CHN; ++i) {
        float w = Wl[(size_t)i * CIN];
        #pragma unroll
        for (int r = 0; r < 8; ++r) acc[r] += xs[r][i] * w;
    }
    float bb = (s == 0) ? bo[o] : 0.f;
    #pragma unroll
    for (int r = 0; r < 8; ++r)
        out[((size_t)(n0 + r) * SDIM + s) * CIN + o] = acc[r] + bb;
}

extern "C" void kernel_launch(void* const* d_in, const int* in_sizes, int n_in,
                              void* d_out, int out_size, void* d_ws, size_t ws_size,
                              hipStream_t stream) {
    const float* q = (const float*)d_in[0];
    const float* k = (const float*)d_in[1];
    const float* v = (const float*)d_in[2];
    const float* envelope = (const float*)d_in[3];
    const float* attn_bias = (const float*)d_in[4];
    const int* atom_index = (const int*)d_in[5];
    const int* batch_index = (const int*)d_in[6];
    const int* edge_map = (const int*)d_in[7];
    const float* Wq = (const float*)d_in[8];
    const float* bq = (const float*)d_in[9];
    const float* Wk = (const float*)d_in[10];
    const float* bk = (const float*)d_in[11];
    const float* Wv = (const float*)d_in[12];
    const float* bv = (const float*)d_in[13];
    const float* gamma = (const float*)d_in[14];
    const float* beta = (const float*)d_in[15];
    const float* Wo = (const float*)d_in[16];
    const float* bo = (const float*)d_in[17];
    float* out = (float*)d_out;

    const size_t SZ_HNF = (size_t)NH * NATOM * FDIM;      // 1,179,648 elems
    const size_t SZ_HNN = (size_t)NH * NATOM * NATOM;     // 2,097,152 elems
    const size_t SZ_TAB = (size_t)NH * NSEG * NATOM;      // 65,536 elems

    char* wsb = (char*)d_ws;
    __hip_bfloat16* qhB = (__hip_bfloat16*)wsb;                         // 2 * SZ_HNF bytes
    __hip_bfloat16* khB = qhB + SZ_HNF;
    __hip_bfloat16* vhT = khB + SZ_HNF;                                 // [h][f][n]
    float* scoresA = (float*)(vhT + SZ_HNF);                            // 4 * SZ_HNN bytes
    __hip_bfloat16* attnB = (__hip_bfloat16*)(scoresA + SZ_HNN);        // 2 * SZ_HNN bytes
    float* E1 = (float*)(attnB + SZ_HNN);
    float* E2 = E1 + SZ_TAB;
    float* maxB = E2 + SZ_TAB;
    int* segStart = (int*)(maxB + 16);
    float* attnOut = scoresA;                 // reuse: scoresA dead after softmax
    float* normed = (float*)qhB;              // reuse: qhB+khB dead after gemm_scores (4.72 MB fits)

    size_t needed = 2 * 3 * SZ_HNF + 4 * SZ_HNN + 2 * SZ_HNN + 4 * 2 * SZ_TAB + 256;
    if (ws_size < needed) return;

    seg_start<<<NEDGE / 256, 256, 0, stream>>>(batch_index, segStart);
    head_maxbias<<<NH, 256, 0, stream>>>(attn_bias, maxB);
    dim3 gLin(NATOM / 8, SDIM);
    so3lin_in_qk<<<gLin, 256, 0, stream>>>(q, Wq, bq, qhB, SCALE);
    so3lin_in_qk<<<gLin, 256, 0, stream>>>(k, Wk, bk, khB, 1.0f);
    so3lin_in_vT<<<gLin, 256, 0, stream>>>(v, Wv, bv, vhT);
    seg_tables<<<dim3(NSEG, NH), 256, 0, stream>>>(atom_index, edge_map, envelope, attn_bias,
                                                   segStart, maxB, E1, E2);
    gemm_scores_mfma<<<dim3(NATOM / 64, NATOM / 64, NH), 256, 0, stream>>>(
        (const ushort*)qhB, (const ushort*)khB, scoresA);
    softmax_agg2<<<dim3(NATOM / SM_ROWS, NH), 256, 0, stream>>>(scoresA, attnB, E1, E2);
    gemm_out_mfma<<<dim3((FDIM + 63) / 64, NATOM / 64, NH), 256, 0, stream>>>(
        (const ushort*)attnB, (const ushort*)vhT, attnOut);
    eqln<<<NATOM, 256, 0, stream>>>(attnOut, gamma, beta, normed);
    so3lin_out<<<gLin, 128, 0, stream>>>(normed, Wo, bo, out);
}

// Round 4
// 114.822 us; speedup vs baseline: 3.4153x; 1.2899x over previous
//
#include <hip/hip_runtime.h>
#include <hip/hip_bf16.h>
#include <math.h>

#define NH 8
#define SDIM 9
#define NSEG 16
#define NATOM 512
#define NEDGE 8192
#define CIN 128
#define CHN 256
#define DH 32
#define FDIM 288            // SDIM*DH
#define EPS 1e-7f
#define SCALE 0.10206207261596577f   // sqrt(32/3)/32

typedef __attribute__((ext_vector_type(8))) short bf16x8;
typedef __attribute__((ext_vector_type(8))) short short8;
typedef __attribute__((ext_vector_type(4))) float f32x4;

// ---------------- block reduce helpers (blockDim.x == 256) ----------------
__device__ inline float blockReduceMax(float v, float* red) {
    #pragma unroll
    for (int off = 32; off; off >>= 1) v = fmaxf(v, __shfl_xor(v, off, 64));
    int lane = threadIdx.x & 63, wid = threadIdx.x >> 6;
    if (lane == 0) red[wid] = v;
    __syncthreads();
    v = fmaxf(fmaxf(red[0], red[1]), fmaxf(red[2], red[3]));
    __syncthreads();
    return v;
}
__device__ inline float blockReduceSum(float v, float* red) {
    #pragma unroll
    for (int off = 32; off; off >>= 1) v += __shfl_xor(v, off, 64);
    int lane = threadIdx.x & 63, wid = threadIdx.x >> 6;
    if (lane == 0) red[wid] = v;
    __syncthreads();
    v = red[0] + red[1] + red[2] + red[3];
    __syncthreads();
    return v;
}

__device__ inline int lower_bound_batch(const int* __restrict__ b, int val) {
    int lo = 0, hi = NEDGE;
    while (lo < hi) {
        int mid = (lo + hi) >> 1;
        if (b[mid] < val) lo = mid + 1; else hi = mid;
    }
    return lo;
}

// ---------------- K0: fused segment prep -> per-(h,seg,atom) tables E1,E2 ----------------
// E1[h,seg,m] = sum_{e in seg, am[e]=m} env[e]   * exp(bias[h,e]-maxB[h])
// E2[h,seg,m] = sum_{e in seg, am[e]=m} env[e]^2 * exp(bias[h,e]-maxB[h])
__global__ void __launch_bounds__(256) seg_prep(const int* __restrict__ batch,
                                                const int* __restrict__ am, const int* __restrict__ emap,
                                                const float* __restrict__ envelope,
                                                const float* __restrict__ attn_bias,
                                                float* __restrict__ E1, float* __restrict__ E2) {
    const int seg = blockIdx.x, h = blockIdx.y;
    __shared__ float e1[NATOM];
    __shared__ float e2[NATOM];
    __shared__ float red[4];
    const int tid = threadIdx.x;
    e1[tid] = 0.f; e1[tid + 256] = 0.f;
    e2[tid] = 0.f; e2[tid + 256] = 0.f;
    // per-head max bias (any upper bound works; shift cancels in the ratio)
    const float* bh = attn_bias + (size_t)h * NEDGE;
    float v = -1e30f;
    for (int e = tid; e < NEDGE; e += 256) v = fmaxf(v, bh[e]);
    const float mb = blockReduceMax(v, red);   // syncthreads inside also covers e1/e2 init
    // segment boundaries via binary search on sorted batch_index
    const int st = lower_bound_batch(batch, seg);
    const int en = lower_bound_batch(batch, seg + 1);
    for (int e = st + tid; e < en; e += 256) {
        int m = am[e], em = emap[e];
        float ev = envelope[em];
        float eb = __expf(bh[em] - mb);
        atomicAdd(&e1[m], ev * eb);
        atomicAdd(&e2[m], ev * ev * eb);
    }
    __syncthreads();
    size_t base = ((size_t)h * NSEG + seg) * NATOM;
    E1[base + tid] = e1[tid]; E1[base + tid + 256] = e1[tid + 256];
    E2[base + tid] = e2[tid]; E2[base + tid + 256] = e2[tid + 256];
}

// ---------------- K1: fused q/k/v so3_linear (CIN=128 -> CHN=256) ----------------
// z=0: q -> qhB (H,N,F) pre-scaled; z=1: k -> khB (H,N,F); z=2: v -> vhT (H,F,N)
__global__ void __launch_bounds__(256) proj_qkv(const float* __restrict__ q, const float* __restrict__ k,
                                                const float* __restrict__ v,
                                                const float* __restrict__ Wq, const float* __restrict__ Wk,
                                                const float* __restrict__ Wv,
                                                const float* __restrict__ bq, const float* __restrict__ bk,
                                                const float* __restrict__ bv,
                                                __hip_bfloat16* __restrict__ qhB,
                                                __hip_bfloat16* __restrict__ khB,
                                                __hip_bfloat16* __restrict__ vhT) {
    const int z = blockIdx.z;
    const float* x = (z == 0) ? q : (z == 1) ? k : v;
    const float* W = (z == 0) ? Wq : (z == 1) ? Wk : Wv;
    const float* bias = (z == 0) ? bq : (z == 1) ? bk : bv;
    const float scale = (z == 0) ? SCALE : 1.0f;
    const int n0 = blockIdx.x * 8;
    const int s = blockIdx.y;
    const int l = (s == 0) ? 0 : ((s < 4) ? 1 : 2);
    __shared__ float xs[8][CIN];
    const int tid = threadIdx.x;
    for (int idx = tid; idx < 8 * CIN; idx += 256) {
        int r = idx >> 7, i = idx & 127;
        xs[r][i] = x[((size_t)(n0 + r) * SDIM + s) * CIN + i];
    }
    __syncthreads();
    const int o = tid;
    const float* Wl = W + (size_t)l * CIN * CHN + o;
    float acc[8] = {0, 0, 0, 0, 0, 0, 0, 0};
    #pragma unroll 4
    for (int i = 0; i < CIN; ++i) {
        float w = Wl[(size_t)i * CHN];
        #pragma unroll
        for (int r = 0; r < 8; ++r) acc[r] += xs[r][i] * w;
    }
    float bb = (s == 0) ? bias[o] : 0.f;
    const int h = o >> 5, dj = o & 31;
    const int f = s * DH + dj;
    if (z < 2) {
        __hip_bfloat16* out = (z == 0) ? qhB : khB;
        #pragma unroll
        for (int r = 0; r < 8; ++r)
            out[((size_t)h * NATOM + (n0 + r)) * FDIM + f] = __float2bfloat16((acc[r] + bb) * scale);
    } else {
        __hip_bfloat16* dst = vhT + ((size_t)h * FDIM + f) * NATOM + n0;
        #pragma unroll
        for (int r = 0; r < 8; ++r) dst[r] = __float2bfloat16(acc[r] + bb);
    }
}

// ---------------- K2: MFMA scores: scoresA[h][n][m] = dot(qhB[h,n,:], khB[h,m,:]) ----------------
__global__ void __launch_bounds__(256) gemm_scores_mfma(const ushort* __restrict__ qhB,
                                                        const ushort* __restrict__ khB,
                                                        float* __restrict__ scoresA) {
    const int h = blockIdx.z;
    const int m0 = blockIdx.x * 64;
    const int n0 = blockIdx.y * 64;
    const int tid = threadIdx.x;
    const int lane = tid & 63, w = tid >> 6;
    const int wr = w >> 1, wc = w & 1;
    const int r = lane & 15, kg = lane >> 4;
    const ushort* A = qhB + (size_t)h * NATOM * FDIM;
    const ushort* B = khB + (size_t)h * NATOM * FDIM;
    const int ar = n0 + 32 * wr + r;
    const int br = m0 + 32 * wc + r;
    f32x4 acc00 = {}, acc01 = {}, acc10 = {}, acc11 = {};
    #pragma unroll
    for (int ks = 0; ks < FDIM / 32; ++ks) {
        const int k0 = ks * 32 + kg * 8;
        bf16x8 a0 = *(const bf16x8*)(A + (size_t)ar * FDIM + k0);
        bf16x8 a1 = *(const bf16x8*)(A + (size_t)(ar + 16) * FDIM + k0);
        bf16x8 b0 = *(const bf16x8*)(B + (size_t)br * FDIM + k0);
        bf16x8 b1 = *(const bf16x8*)(B + (size_t)(br + 16) * FDIM + k0);
        acc00 = __builtin_amdgcn_mfma_f32_16x16x32_bf16(a0, b0, acc00, 0, 0, 0);
        acc01 = __builtin_amdgcn_mfma_f32_16x16x32_bf16(a0, b1, acc01, 0, 0, 0);
        acc10 = __builtin_amdgcn_mfma_f32_16x16x32_bf16(a1, b0, acc10, 0, 0, 0);
        acc11 = __builtin_amdgcn_mfma_f32_16x16x32_bf16(a1, b1, acc11, 0, 0, 0);
    }
    #define STORE_SC(ACC, I, J) { \
        int row = n0 + 32 * wr + (I) * 16 + kg * 4; \
        int col = m0 + 32 * wc + (J) * 16 + r; \
        float* dst = scoresA + ((size_t)h * NATOM + row) * NATOM + col; \
        dst[0] = ACC[0]; dst[NATOM] = ACC[1]; dst[2 * NATOM] = ACC[2]; dst[3 * NATOM] = ACC[3]; }
    STORE_SC(acc00, 0, 0) STORE_SC(acc01, 0, 1) STORE_SC(acc10, 1, 0) STORE_SC(acc11, 1, 1)
    #undef STORE_SC
}

// ---------------- K3: wave-parallel collapsed segmented softmax (fp32 scores -> bf16 attn) ----------------
// attnA[h,n,m] = es[m] * sum_g E2[h,g,m] / (sum_m' es[m']*E1[h,g,m'] + 1e-30)
// One wave per row; no block barriers in the row loop.
#define SMW_RPW 2
__global__ void __launch_bounds__(256) softmax_agg3(const float* __restrict__ scoresA,
                                                    ushort* __restrict__ attnB,
                                                    const float* __restrict__ E1,
                                                    const float* __restrict__ E2) {
    const int h = blockIdx.y;
    const int n0 = blockIdx.x * (4 * SMW_RPW);
    __shared__ float E1s[NSEG][NATOM];   // 32 KB
    __shared__ float E2s[NSEG][NATOM];   // 32 KB
    const int tid = threadIdx.x;
    const float* e1g = E1 + (size_t)h * NSEG * NATOM;
    const float* e2g = E2 + (size_t)h * NSEG * NATOM;
    for (int i = tid * 4; i < NSEG * NATOM; i += 1024) {
        *(float4*)&((float*)E1s)[i] = *(const float4*)&e1g[i];
        *(float4*)&((float*)E2s)[i] = *(const float4*)&e2g[i];
    }
    __syncthreads();
    const int lane = tid & 63, wid = tid >> 6;
    const int m0 = lane * 8;
    for (int rr = 0; rr < SMW_RPW; ++rr) {
        const int row = n0 + wid * SMW_RPW + rr;
        const float* srow = scoresA + ((size_t)h * NATOM + row) * NATOM;
        float4 sa = *(const float4*)(srow + m0);
        float4 sb = *(const float4*)(srow + m0 + 4);
        float s[8] = {sa.x, sa.y, sa.z, sa.w, sb.x, sb.y, sb.z, sb.w};
        float mx = fmaxf(fmaxf(fmaxf(s[0], s[1]), fmaxf(s[2], s[3])),
                         fmaxf(fmaxf(s[4], s[5]), fmaxf(s[6], s[7])));
        #pragma unroll
        for (int off = 32; off; off >>= 1) mx = fmaxf(mx, __shfl_xor(mx, off, 64));
        float es[8];
        #pragma unroll
        for (int j = 0; j < 8; ++j) es[j] = __expf(s[j] - mx);
        float D[NSEG];
        #pragma unroll
        for (int g = 0; g < NSEG; ++g) {
            float4 p = *(const float4*)&E1s[g][m0];
            float4 p2 = *(const float4*)&E1s[g][m0 + 4];
            D[g] = es[0] * p.x + es[1] * p.y + es[2] * p.z + es[3] * p.w
                 + es[4] * p2.x + es[5] * p2.y + es[6] * p2.z + es[7] * p2.w;
        }
        #pragma unroll
        for (int g = 0; g < NSEG; ++g) {
            float vv = D[g];
            #pragma unroll
            for (int off = 32; off; off >>= 1) vv += __shfl_xor(vv, off, 64);
            D[g] = vv;
        }
        float w[8] = {};
        #pragma unroll
        for (int g = 0; g < NSEG; ++g) {
            float iv = 1.0f / (D[g] + 1e-30f);
            float4 p = *(const float4*)&E2s[g][m0];
            float4 p2 = *(const float4*)&E2s[g][m0 + 4];
            w[0] += iv * p.x;  w[1] += iv * p.y;  w[2] += iv * p.z;  w[3] += iv * p.w;
            w[4] += iv * p2.x; w[5] += iv * p2.y; w[6] += iv * p2.z; w[7] += iv * p2.w;
        }
        ushort* arow = attnB + ((size_t)h * NATOM + row) * NATOM;
        short8 ov;
        #pragma unroll
        for (int j = 0; j < 8; ++j) {
            __hip_bfloat16 bv = __float2bfloat16(es[j] * w[j]);
            ov[j] = *(short*)&bv;
        }
        *(short8*)(arow + m0) = ov;
    }
}

// ---------------- K4: MFMA out: attnOut[n][s][h*32+dj] = sum_m attnB[h,n,m]*vhT[h,f,m] ----------------
__global__ void __launch_bounds__(256) gemm_out_mfma(const ushort* __restrict__ attnB,
                                                     const ushort* __restrict__ vhT,
                                                     float* __restrict__ attnOut) {
    const int h = blockIdx.z;
    const int f0 = blockIdx.x * 64;
    const int n0 = blockIdx.y * 64;
    const int tid = threadIdx.x;
    const int lane = tid & 63, w = tid >> 6;
    const int wr = w >> 1, wc = w & 1;
    const int r = lane & 15, kg = lane >> 4;
    const ushort* A = attnB + (size_t)h * NATOM * NATOM;
    const ushort* B = vhT + (size_t)h * FDIM * NATOM;
    const int ar = n0 + 32 * wr + r;
    const int br = f0 + 32 * wc + r;
    const bool b0ok = (f0 + 32 * wc) < FDIM;
    const bool b1ok = (f0 + 32 * wc + 16) < FDIM;
    f32x4 acc00 = {}, acc01 = {}, acc10 = {}, acc11 = {};
    const bf16x8 bz = {};
    #pragma unroll 4
    for (int ks = 0; ks < NATOM / 32; ++ks) {
        const int k0 = ks * 32 + kg * 8;
        bf16x8 a0 = *(const bf16x8*)(A + (size_t)ar * NATOM + k0);
        bf16x8 a1 = *(const bf16x8*)(A + (size_t)(ar + 16) * NATOM + k0);
        bf16x8 b0 = b0ok ? *(const bf16x8*)(B + (size_t)br * NATOM + k0) : bz;
        bf16x8 b1 = b1ok ? *(const bf16x8*)(B + (size_t)(br + 16) * NATOM + k0) : bz;
        acc00 = __builtin_amdgcn_mfma_f32_16x16x32_bf16(a0, b0, acc00, 0, 0, 0);
        acc01 = __builtin_amdgcn_mfma_f32_16x16x32_bf16(a0, b1, acc01, 0, 0, 0);
        acc10 = __builtin_amdgcn_mfma_f32_16x16x32_bf16(a1, b0, acc10, 0, 0, 0);
        acc11 = __builtin_amdgcn_mfma_f32_16x16x32_bf16(a1, b1, acc11, 0, 0, 0);
    }
    #define STORE_OUT(ACC, I, J) { \
        int row = n0 + 32 * wr + (I) * 16 + kg * 4; \
        int f = f0 + 32 * wc + (J) * 16 + r; \
        if (f < FDIM) { \
            int s = f >> 5, dj = f & 31; \
            float* dst = attnOut + ((size_t)row * SDIM + s) * CHN + h * DH + dj; \
            dst[0] = ACC[0]; dst[SDIM * CHN] = ACC[1]; dst[2 * SDIM * CHN] = ACC[2]; dst[3 * SDIM * CHN] = ACC[3]; } }
    STORE_OUT(acc00, 0, 0) STORE_OUT(acc01, 0, 1) STORE_OUT(acc10, 1, 0) STORE_OUT(acc11, 1, 1)
    #undef STORE_OUT
}

// ---------------- K5: equivariant layernorm ----------------
__global__ void __launch_bounds__(256) eqln(const float* __restrict__ xin, const float* __restrict__ gamma,
                                            const float* __restrict__ beta, float* __restrict__ outn) {
    const int n = blockIdx.x;
    const int c = threadIdx.x;
    __shared__ float red[4];
    float xv[SDIM];
    #pragma unroll
    for (int s = 0; s < SDIM; ++s) xv[s] = xin[((size_t)n * SDIM + s) * CHN + c];
    float mu = blockReduceSum(xv[0], red) * (1.0f / CHN);
    float dv = xv[0] - mu;
    float var = blockReduceSum(dv * dv, red) * (1.0f / CHN);
    float y0 = dv / sqrtf(var + EPS) * gamma[c] + beta[c];
    outn[(size_t)n * SDIM * CHN + c] = y0;
    float n2 = (xv[1] * xv[1] + xv[2] * xv[2] + xv[3] * xv[3]) * (1.0f / 3.0f);
    float ms = blockReduceSum(n2, red) * (1.0f / CHN);
    float inv1 = 1.0f / sqrtf(ms + EPS);
    #pragma unroll
    for (int s = 1; s < 4; ++s)
        outn[((size_t)n * SDIM + s) * CHN + c] = xv[s] * inv1 * gamma[CHN + c];
    float n22 = (xv[4] * xv[4] + xv[5] * xv[5] + xv[6] * xv[6] + xv[7] * xv[7] + xv[8] * xv[8]) * (1.0f / 5.0f);
    float ms2 = blockReduceSum(n22, red) * (1.0f / CHN);
    float inv2 = 1.0f / sqrtf(ms2 + EPS);
    #pragma unroll
    for (int s = 4; s < SDIM; ++s)
        outn[((size_t)n * SDIM + s) * CHN + c] = xv[s] * inv2 * gamma[2 * CHN + c];
}

// ---------------- K6: final so3_linear (CHN=256 -> CIN=128) ----------------
__global__ void __launch_bounds__(128) so3lin_out(const float* __restrict__ xn, const float* __restrict__ Wo,
                                                  const float* __restrict__ bo, float* __restrict__ out) {
    const int n0 = blockIdx.x * 8;
    const int s = blockIdx.y;
    const int l = (s == 0) ? 0 : ((s < 4) ? 1 : 2);
    __shared__ float xs[8][CHN];
    const int tid = threadIdx.x;
    for (int idx = tid; idx < 8 * CHN; idx += 128) {
        int r = idx >> 8, i = idx & 255;
        xs[r][i] = xn[((size_t)(n0 + r) * SDIM + s) * CHN + i];
    }
    __syncthreads();
    const int o = tid;
    const float* Wl = Wo + (size_t)l * CHN * CIN + o;
    float acc[8] = {0, 0, 0, 0, 0, 0, 0, 0};
    #pragma unroll 4
    for (int i = 0; i < CHN; ++i) {
        float w = Wl[(size_t)i * CIN];
        #pragma unroll
        for (int r = 0; r < 8; ++r) acc[r] += xs[r][i] * w;
    }
    float bb = (s == 0) ? bo[o] : 0.f;
    #pragma unroll
    for (int r = 0; r < 8; ++r)
        out[((size_t)(n0 + r) * SDIM + s) * CIN + o] = acc[r] + bb;
}

extern "C" void kernel_launch(void* const* d_in, const int* in_sizes, int n_in,
                              void* d_out, int out_size, void* d_ws, size_t ws_size,
                              hipStream_t stream) {
    const float* q = (const float*)d_in[0];
    const float* k = (const float*)d_in[1];
    const float* v = (const float*)d_in[2];
    const float* envelope = (const float*)d_in[3];
    const float* attn_bias = (const float*)d_in[4];
    const int* atom_index = (const int*)d_in[5];
    const int* batch_index = (const int*)d_in[6];
    const int* edge_map = (const int*)d_in[7];
    const float* Wq = (const float*)d_in[8];
    const float* bq = (const float*)d_in[9];
    const float* Wk = (const float*)d_in[10];
    const float* bk = (const float*)d_in[11];
    const float* Wv = (const float*)d_in[12];
    const float* bv = (const float*)d_in[13];
    const float* gamma = (const float*)d_in[14];
    const float* beta = (const float*)d_in[15];
    const float* Wo = (const float*)d_in[16];
    const float* bo = (const float*)d_in[17];
    float* out = (float*)d_out;

    const size_t SZ_HNF = (size_t)NH * NATOM * FDIM;      // 1,179,648 elems
    const size_t SZ_HNN = (size_t)NH * NATOM * NATOM;     // 2,097,152 elems
    const size_t SZ_TAB = (size_t)NH * NSEG * NATOM;      // 65,536 elems

    char* wsb = (char*)d_ws;
    __hip_bfloat16* qhB = (__hip_bfloat16*)wsb;                         // 2 * SZ_HNF bytes
    __hip_bfloat16* khB = qhB + SZ_HNF;
    __hip_bfloat16* vhT = khB + SZ_HNF;                                 // [h][f][n]
    float* scoresA = (float*)(vhT + SZ_HNF);                            // 4 * SZ_HNN bytes
    __hip_bfloat16* attnB = (__hip_bfloat16*)(scoresA + SZ_HNN);        // 2 * SZ_HNN bytes
    float* E1 = (float*)(attnB + SZ_HNN);
    float* E2 = E1 + SZ_TAB;
    float* attnOut = scoresA;                 // reuse: scoresA dead after softmax
    float* normed = (float*)qhB;              // reuse: qhB+khB dead after gemm_scores (4.72 MB)

    size_t needed = 2 * 3 * SZ_HNF + 4 * SZ_HNN + 2 * SZ_HNN + 4 * 2 * SZ_TAB + 256;
    if (ws_size < needed) return;

    seg_prep<<<dim3(NSEG, NH), 256, 0, stream>>>(batch_index, atom_index, edge_map,
                                                 envelope, attn_bias, E1, E2);
    proj_qkv<<<dim3(NATOM / 8, SDIM, 3), 256, 0, stream>>>(q, k, v, Wq, Wk, Wv, bq, bk, bv,
                                                           qhB, khB, vhT);
    gemm_scores_mfma<<<dim3(NATOM / 64, NATOM / 64, NH), 256, 0, stream>>>(
        (const ushort*)qhB, (const ushort*)khB, scoresA);
    softmax_agg3<<<dim3(NATOM / (4 * SMW_RPW), NH), 256, 0, stream>>>(
        scoresA, (ushort*)attnB, E1, E2);
    gemm_out_mfma<<<dim3((FDIM + 63) / 64, NATOM / 64, NH), 256, 0, stream>>>(
        (const ushort*)attnB, (const ushort*)vhT, attnOut);
    eqln<<<NATOM, 256, 0, stream>>>(attnOut, gamma, beta, normed);
    so3lin_out<<<dim3(NATOM / 8, SDIM), 128, 0, stream>>>(normed, Wo, bo, out);
}